// Round 1
// baseline (255.569 us; speedup 1.0000x reference)
//
#include <hip/hip_runtime.h>

// KAN layer forward, MI355X. Inputs AND outputs are float32 buffers.
// Outputs (flat concat, f32): y_out[1024,128], preacts[1024,128,128],
// postacts[1024,128,128], postspline[1024,128,128].
//
// R5 -> R6: R5 was VMEM-issue/latency bound, not HBM bound: 6 scalar 4B
// stores per j (256B/wave-instr) + 6 serial shuffles per j gave ~1.9 TB/s
// effective writes vs the ~6.6 TB/s the fill kernels sustain. Now each lane
// owns an i-quad (i = 4*(lane&31)..+3) and each wave does two adjacent j per
// iteration (half-wave per j):
//   - all big-output stores are float4 -> 1KB contiguous per wave store instr
//   - mask/scales are float4 loads; coef is 8x b128 per lane per j
//   - y_out reduction: 5 width-32 shuffle steps per TWO j (was 6 per j)
// Grid/block unchanged: 2048 blocks (batch row x j-half), 256 threads.
//
// Phase 1 (threads 0..127): exact Cox-de Boor basis (matches extend_grid +
// b_batch) + silu into LDS, basis stored TRANSPOSED sBT[m][i] so phase-2
// fragment loads are clean float4 reads.

#define IN_DIM  128
#define OUT_DIM 128
#define NUMG    5
#define KORD    3
#define NB      8          // NUMG + KORD basis functions
#define SIZE    (IN_DIM * OUT_DIM)
#define BATCH   1024

__global__ __launch_bounds__(256) void kan_fused(
    const float* __restrict__ x,
    const float* __restrict__ grid,
    const float* __restrict__ coef,
    const float* __restrict__ scale_base,
    const float* __restrict__ scale_sp,
    const float* __restrict__ mask,
    float* __restrict__ out)
{
    __shared__ float sBT[NB][IN_DIM];   // transposed: [basis_m][i]
    __shared__ float sSilu[IN_DIM];
    __shared__ float sXv[IN_DIM];

    const int tid  = threadIdx.x;
    const int b    = blockIdx.x >> 1;          // batch row
    const int half = blockIdx.x & 1;           // j half: [0,64) or [64,128)

    // ---- Phase 1: basis + silu for i = tid (threads 0..127) ----
    if (tid < IN_DIM) {
        const int i = tid;
        const float xv = x[b * IN_DIM + i];

        float gr[NUMG + 1];
        #pragma unroll
        for (int r = 0; r <= NUMG; ++r) gr[r] = grid[i * (NUMG + 1) + r];

        const float h = (gr[NUMG] - gr[0]) * (1.0f / NUMG);
        float t[NUMG + 1 + 2 * KORD];             // 12 knots
        t[2] = gr[0] - h; t[1] = t[2] - h; t[0] = t[1] - h;
        #pragma unroll
        for (int r = 0; r <= NUMG; ++r) t[KORD + r] = gr[r];
        t[9] = gr[NUMG] + h; t[10] = t[9] + h; t[11] = t[10] + h;

        float B[NUMG + 2 * KORD];                 // 11 -> 10 -> 9 -> 8
        #pragma unroll
        for (int m = 0; m < NUMG + 2 * KORD; ++m)
            B[m] = (xv >= t[m] && xv < t[m + 1]) ? 1.0f : 0.0f;
        #pragma unroll
        for (int p = 1; p <= KORD; ++p) {
            #pragma unroll
            for (int m = 0; m < NUMG + 2 * KORD - p; ++m) {
                B[m] = (xv - t[m]) / (t[m + p] - t[m]) * B[m]
                     + (t[m + p + 1] - xv) / (t[m + p + 1] - t[m + 1]) * B[m + 1];
            }
        }

        #pragma unroll
        for (int m = 0; m < NB; ++m) sBT[m][i] = B[m];
        sSilu[i] = xv / (1.0f + __expf(-xv));
        sXv[i]   = xv;
    }
    __syncthreads();

    // ---- Phase 2: lane owns i-quad i4..i4+3; wave does j pairs ----
    const int lane = tid & 63;
    const int w    = tid >> 6;
    const int il   = lane & 31;                // i-quad index
    const int jh   = lane >> 5;                // which j of the pair
    const int i4   = il << 2;

    float bas[NB][4];                          // [m][k], fully register-resident
    #pragma unroll
    for (int m = 0; m < NB; ++m) {
        const float4 v = *(const float4*)&sBT[m][i4];
        bas[m][0] = v.x; bas[m][1] = v.y; bas[m][2] = v.z; bas[m][3] = v.w;
    }
    const float4 slv = *(const float4*)&sSilu[i4];
    const float4 pxv = *(const float4*)&sXv[i4];
    const float slA[4] = {slv.x, slv.y, slv.z, slv.w};

    float* out_y   = out;
    float* out_pre = out + BATCH * OUT_DIM;
    float* out_act = out_pre + (size_t)BATCH * SIZE;
    float* out_spl = out_act + (size_t)BATCH * SIZE;

    const int jbase = half * 64 + w * 16 + jh; // wave covers 16 j, 2 at a time
    const float4* cp = (const float4*)coef;

    #pragma unroll 2
    for (int jj = 0; jj < 8; ++jj) {
        const int j = jbase + 2 * jj;
        const int s = j * IN_DIM + i4;         // coef/scale row base for k=0

        float4 qa[4], qb[4];
        #pragma unroll
        for (int k = 0; k < 4; ++k) {
            qa[k] = cp[2 * (s + k)];
            qb[k] = cp[2 * (s + k) + 1];
        }
        const float4 mkv = *(const float4*)&mask[s];
        const float4 sbv = *(const float4*)&scale_base[s];
        const float4 ssv = *(const float4*)&scale_sp[s];
        const float mkA[4] = {mkv.x, mkv.y, mkv.z, mkv.w};
        const float sbA[4] = {sbv.x, sbv.y, sbv.z, sbv.w};
        const float ssA[4] = {ssv.x, ssv.y, ssv.z, ssv.w};

        float sp[4], y[4];
        #pragma unroll
        for (int k = 0; k < 4; ++k) {
            float r =        qa[k].x * bas[0][k];
            r = fmaf(qa[k].y, bas[1][k], r);
            r = fmaf(qa[k].z, bas[2][k], r);
            r = fmaf(qa[k].w, bas[3][k], r);
            r = fmaf(qb[k].x, bas[4][k], r);
            r = fmaf(qb[k].y, bas[5][k], r);
            r = fmaf(qb[k].z, bas[6][k], r);
            r = fmaf(qb[k].w, bas[7][k], r);
            sp[k] = r;
            y[k]  = mkA[k] * (sbA[k] * slA[k] + ssA[k] * r);
        }

        const size_t e = (size_t)b * SIZE + (size_t)s;
        *(float4*)&out_pre[e] = pxv;                            // x broadcast
        *(float4*)&out_act[e] = make_float4(y[0], y[1], y[2], y[3]);
        *(float4*)&out_spl[e] = make_float4(sp[0], sp[1], sp[2], sp[3]);

        // y_out[b][j] = sum over i: reduce across the 32-lane half-wave.
        float acc = (y[0] + y[1]) + (y[2] + y[3]);
        #pragma unroll
        for (int off = 16; off > 0; off >>= 1)
            acc += __shfl_down(acc, off, 32);
        if (il == 0) out_y[b * OUT_DIM + j] = acc;
    }
}

extern "C" void kernel_launch(void* const* d_in, const int* in_sizes, int n_in,
                              void* d_out, int out_size, void* d_ws, size_t ws_size,
                              hipStream_t stream)
{
    hipLaunchKernelGGL(kan_fused, dim3(BATCH * 2), dim3(256), 0, stream,
                       (const float*)d_in[0], (const float*)d_in[1],
                       (const float*)d_in[2], (const float*)d_in[3],
                       (const float*)d_in[4], (const float*)d_in[5],
                       (float*)d_out);
}

// Round 2
// 220.405 us; speedup vs baseline: 1.1595x; 1.1595x over previous
//
#include <hip/hip_runtime.h>

// KAN layer forward, MI355X. Inputs AND outputs are float32 buffers.
// Outputs (flat concat, f32): y_out[1024,128], preacts[1024,128,128],
// postacts[1024,128,128], postspline[1024,128,128].
//
// R6 -> R7: R6's lane<->i-quad coef loads had 128B lane stride -> 64 cache
// lines touched per instruction, 16B used each. Line-request arithmetic:
// +8K lines/block vs R5 = ~27us, matching the observed +30us regression.
// The kernel is TA line-throughput bound. Now EVERY global instruction is
// fully contiguous:
//   - coef: lane l loads float4 #(j*256+64q+l) -> 1KB contiguous per instr
//     (16 lines, 100% covered). Lane holds m-half (l&1) of i=32q+(l>>1).
//   - basis fragment per (i,m-half) loaded ONCE to registers pre-loop
//     (mapping is j-independent): partial = dot4(coef, basq).
//   - partials for 2 j are bounced through per-wave LDS (sPart, 2KB/wave,
//     no barrier needed - within-wave lgkm ordering) to re-map lanes to
//     (i-quad, j-half) -> keep R6's 1KB-contiguous float4 stores and
//     float4 mask/scale loads.
// Line count/block: coef 4K + stores 1.5K + scales 0.75K ~= 6.3K
// (R5 ~11K, R6 ~19K) -> TA ~21us, under the ~31us HBM write floor.

#define IN_DIM  128
#define OUT_DIM 128
#define NUMG    5
#define KORD    3
#define NB      8          // NUMG + KORD basis functions
#define SIZE    (IN_DIM * OUT_DIM)
#define BATCH   1024

__global__ __launch_bounds__(256) void kan_fused(
    const float* __restrict__ x,
    const float* __restrict__ grid,
    const float* __restrict__ coef,
    const float* __restrict__ scale_base,
    const float* __restrict__ scale_sp,
    const float* __restrict__ mask,
    float* __restrict__ out)
{
    __shared__ float sB[IN_DIM][NB];        // [i][m]
    __shared__ float sSilu[IN_DIM];
    __shared__ float sXv[IN_DIM];
    __shared__ float sPart[4][2][2][IN_DIM]; // [wave][j-of-pair][m-half][i]

    const int tid  = threadIdx.x;
    const int b    = blockIdx.x >> 1;          // batch row
    const int half = blockIdx.x & 1;           // j half: [0,64) or [64,128)

    // ---- Phase 1: basis + silu for i = tid (threads 0..127) ----
    if (tid < IN_DIM) {
        const int i = tid;
        const float xv = x[b * IN_DIM + i];

        float gr[NUMG + 1];
        #pragma unroll
        for (int r = 0; r <= NUMG; ++r) gr[r] = grid[i * (NUMG + 1) + r];

        const float h = (gr[NUMG] - gr[0]) * (1.0f / NUMG);
        float t[NUMG + 1 + 2 * KORD];             // 12 knots
        t[2] = gr[0] - h; t[1] = t[2] - h; t[0] = t[1] - h;
        #pragma unroll
        for (int r = 0; r <= NUMG; ++r) t[KORD + r] = gr[r];
        t[9] = gr[NUMG] + h; t[10] = t[9] + h; t[11] = t[10] + h;

        float B[NUMG + 2 * KORD];                 // 11 -> 10 -> 9 -> 8
        #pragma unroll
        for (int m = 0; m < NUMG + 2 * KORD; ++m)
            B[m] = (xv >= t[m] && xv < t[m + 1]) ? 1.0f : 0.0f;
        #pragma unroll
        for (int p = 1; p <= KORD; ++p) {
            #pragma unroll
            for (int m = 0; m < NUMG + 2 * KORD - p; ++m) {
                B[m] = (xv - t[m]) / (t[m + p] - t[m]) * B[m]
                     + (t[m + p + 1] - xv) / (t[m + p + 1] - t[m + 1]) * B[m + 1];
            }
        }

        *(float4*)&sB[i][0] = make_float4(B[0], B[1], B[2], B[3]);
        *(float4*)&sB[i][4] = make_float4(B[4], B[5], B[6], B[7]);
        sSilu[i] = xv / (1.0f + __expf(-xv));
        sXv[i]   = xv;
    }
    __syncthreads();

    const int lane = tid & 63;
    const int w    = tid >> 6;
    const int a    = lane >> 1;                // i sub-index for loads
    const int mh   = lane & 1;                 // which m-half this lane dots
    const int il   = lane & 31;                // i-quad index for stores
    const int jh   = lane >> 5;                // which j of the pair (stores)
    const int i4   = il << 2;

    // Basis fragments: j-independent, load once. basq[q] pairs with the
    // coef float4 this lane loads at slot q (i = 32q + a, m-half = mh).
    float4 basq[4];
    #pragma unroll
    for (int q = 0; q < 4; ++q)
        basq[q] = *(const float4*)&sB[32 * q + a][4 * mh];

    const float4 slv = *(const float4*)&sSilu[i4];
    const float4 pxv = *(const float4*)&sXv[i4];
    const float slA[4] = {slv.x, slv.y, slv.z, slv.w};

    float* out_y   = out;
    float* out_pre = out + BATCH * OUT_DIM;
    float* out_act = out_pre + (size_t)BATCH * SIZE;
    float* out_spl = out_act + (size_t)BATCH * SIZE;

    const int jbase = half * 64 + w * 16;      // wave owns 16 j, 2 per iter
    const float4* cp = (const float4*)coef;

    #pragma unroll 2
    for (int jj = 0; jj < 8; ++jj) {
        const int j0 = jbase + 2 * jj;

        // 8 coef loads, each 1KB fully contiguous (16 lines, 100% covered)
        float4 cf[2][4];
        #pragma unroll
        for (int jp = 0; jp < 2; ++jp)
            #pragma unroll
            for (int q = 0; q < 4; ++q)
                cf[jp][q] = cp[(size_t)(j0 + jp) * 256 + 64 * q + lane];

        // partial dots -> per-wave LDS bounce (no barrier: within-wave)
        #pragma unroll
        for (int jp = 0; jp < 2; ++jp) {
            #pragma unroll
            for (int q = 0; q < 4; ++q) {
                const float4 c = cf[jp][q];
                const float4 bq = basq[q];
                float r =        c.x * bq.x;
                r = fmaf(c.y, bq.y, r);
                r = fmaf(c.z, bq.z, r);
                r = fmaf(c.w, bq.w, r);
                sPart[w][jp][mh][32 * q + a] = r;
            }
        }

        // re-mapped read-back: lane owns (i-quad i4, j = j0+jh)
        const float4 spE = *(const float4*)&sPart[w][jh][0][i4];
        const float4 spO = *(const float4*)&sPart[w][jh][1][i4];
        const float spA[4] = {spE.x + spO.x, spE.y + spO.y,
                              spE.z + spO.z, spE.w + spO.w};

        const int sS = (j0 + jh) * IN_DIM + i4;
        const float4 mkv = *(const float4*)&mask[sS];
        const float4 sbv = *(const float4*)&scale_base[sS];
        const float4 ssv = *(const float4*)&scale_sp[sS];
        const float mkA[4] = {mkv.x, mkv.y, mkv.z, mkv.w};
        const float sbA[4] = {sbv.x, sbv.y, sbv.z, sbv.w};
        const float ssA[4] = {ssv.x, ssv.y, ssv.z, ssv.w};

        float y[4];
        #pragma unroll
        for (int k = 0; k < 4; ++k)
            y[k] = mkA[k] * (sbA[k] * slA[k] + ssA[k] * spA[k]);

        const size_t e = (size_t)b * SIZE + (size_t)sS;
        *(float4*)&out_pre[e] = pxv;                            // x broadcast
        *(float4*)&out_act[e] = make_float4(y[0], y[1], y[2], y[3]);
        *(float4*)&out_spl[e] = make_float4(spA[0], spA[1], spA[2], spA[3]);

        // y_out[b][j0+jh] = sum over i: width-32 half-wave reduction
        float acc = (y[0] + y[1]) + (y[2] + y[3]);
        #pragma unroll
        for (int off = 16; off > 0; off >>= 1)
            acc += __shfl_down(acc, off, 32);
        if (il == 0) out_y[b * OUT_DIM + j0 + jh] = acc;
    }
}

extern "C" void kernel_launch(void* const* d_in, const int* in_sizes, int n_in,
                              void* d_out, int out_size, void* d_ws, size_t ws_size,
                              hipStream_t stream)
{
    hipLaunchKernelGGL(kan_fused, dim3(BATCH * 2), dim3(256), 0, stream,
                       (const float*)d_in[0], (const float*)d_in[1],
                       (const float*)d_in[2], (const float*)d_in[3],
                       (const float*)d_in[4], (const float*)d_in[5],
                       (float*)d_out);
}